// Round 4
// baseline (452.112 us; speedup 1.0000x reference)
//
#include <hip/hip_runtime.h>
#include <cstdint>
#include <cstddef>

// SearchTransfer on MI355X (gfx950), fp32.
// B=4, C=64, H=W=64, L=4096, K=9C=576.
//
// Algebra:
//  - lr-patch norm is a positive per-column scalar -> cannot change argmax; dropped.
//  - S[a,b] = sum_{i,j} D[a+d, b+d], D = ref_flat^T * lr_flat (K=64).
//  - E-tile(r1,r2) = x-band of D-tile (register shuffles, R3-validated).
//  - S-tile(t-1+k, t-1) = E(t-2)+E(t-1)+E(t) along diagonal k: fused streaming with
//    running partials P,Q. NO E materialization (R2/R3 were pinned at ~45us/batch by
//    the 64 MiB E write at ~1.5 TB/s). Only 8B argmax keys leave the kernel.

#define BATCH 4
#define CCH 64
#define LPIX 4096
#define SEG 8
typedef unsigned long long u64;

__device__ __forceinline__ u64 packKey(float v, int idx) {
    unsigned int bits = __float_as_uint(v);
    unsigned int m = (bits & 0x80000000u) ? ~bits : (bits | 0x80000000u);
    // low 32 = ~idx so that larger key == smaller index on equal value
    return ((u64)m << 32) | (unsigned int)(~(unsigned int)idx);
}

// ---- prep: refT[b][p][c] transpose + ssq[b][p] = sum_c ref^2 -------------
__global__ __launch_bounds__(256) void prep_kernel(const float* __restrict__ ref,
                                                   float* __restrict__ refT,
                                                   float* __restrict__ ssq) {
    __shared__ float s[64 * 65];
    __shared__ float part[256];
    int pt = blockIdx.x, b = blockIdx.y, tid = threadIdx.x;
    const float* rb = ref + ((size_t)b * CCH) * LPIX + pt * 64;
    for (int k = 0; k < 16; ++k) {
        int n = tid + 256 * k;           // n = c*64 + p
        int c = n >> 6, p = n & 63;
        s[c * 65 + p] = rb[(size_t)c * LPIX + p];
    }
    __syncthreads();
    {
        int p = tid & 63, g = tid >> 6;
        float acc = 0.f;
        for (int c = g * 16; c < g * 16 + 16; ++c) { float v = s[c * 65 + p]; acc += v * v; }
        part[g * 64 + p] = acc;
    }
    __syncthreads();
    if (tid < 64) {
        float v = part[tid] + part[64 + tid] + part[128 + tid] + part[192 + tid];
        ssq[b * LPIX + pt * 64 + tid] = v;
    }
    float* tb = refT + ((size_t)b * LPIX + pt * 64) * 64;
    for (int k = 0; k < 16; ++k) {
        int n = tid + 256 * k;           // n = p*64 + c
        int p = n >> 6, c = n & 63;
        tb[n] = s[c * 65 + p];
    }
}

// ---- inv[b][p] = 1 / max(sqrt(3x3 box of ssq), 1e-12) --------------------
__global__ __launch_bounds__(256) void invnorm_kernel(const float* __restrict__ ssq,
                                                      float* __restrict__ inv) {
    int t = blockIdx.x * 256 + threadIdx.x;      // over BATCH*LPIX
    int b = t >> 12, p = t & 4095;
    int y = p >> 6, x = p & 63;
    const float* sb = ssq + b * LPIX;
    float n2 = 0.f;
    for (int i = -1; i <= 1; ++i)
        for (int j = -1; j <= 1; ++j) {
            int yy = y + i, xx = x + j;
            if (yy >= 0 && yy < 64 && xx >= 0 && xx < 64) n2 += sb[yy * 64 + xx];
        }
    inv[t] = 1.0f / fmaxf(sqrtf(n2), 1e-12f);
}

// ---- fused diagonal GEMM + band + argmax ---------------------------------
// One wave per diagonal segment. grid = (127 diagonals, 8 chunks, batch).
// Wave computes E(t) tiles (64x64 in regs, 8x8/thread) for t in [t0-1, t1],
// maintains P = E(t-2)+E(t-1), Q = E(t-1); after adding E(t), S(t-1) = P+E is
// complete -> per-column argmax -> shfl-reduce -> atomicMax of packed keys.
__global__ __launch_bounds__(64) void diag_kernel(const float* __restrict__ ref,
                                                  const float* __restrict__ lr,
                                                  const float* __restrict__ inv,
                                                  u64* __restrict__ packed) {
    __shared__ __align__(16) float As[32 * 64];   // half-K staging (channels h*32..)
    __shared__ __align__(16) float Bs[32 * 64];
    int k = (int)blockIdx.x - 63;
    int b = blockIdx.z;
    int t_lo = k < 0 ? -k : 0;
    int t_hi = 64 - (k > 0 ? k : 0);
    int t0i = t_lo + (int)blockIdx.y * SEG;
    if (t0i >= t_hi) return;
    int t1i = t0i + SEG < t_hi ? t0i + SEG : t_hi;

    const float* refb = ref + (size_t)b * CCH * LPIX;
    const float* lrb  = lr  + (size_t)b * CCH * LPIX;
    const float* invb = inv + b * LPIX;
    u64* pkb = packed + (size_t)b * LPIX;

    int lane = threadIdx.x;
    int rg = lane >> 3, cg = lane & 7;
    bool rgt = rg > 0, rlt = rg < 7, cgt = cg > 0, clt = cg < 7;

    float P[8][8] = {}, Q[8][8] = {};

    for (int t = t0i - 1; t <= t1i; ++t) {
        bool tv = (t >= t_lo) && (t < t_hi);
        bool fin = (t - 1 >= t0i) && (t - 1 < t1i);
        int yprow = (t - 1 + k) << 6;            // S(t-1) row block * 64
        float iv[8], bv[8];
        int bi[8];
        if (fin) {
            float4 iv0 = *(const float4*)&invb[yprow + rg * 8];
            float4 iv1 = *(const float4*)&invb[yprow + rg * 8 + 4];
            iv[0] = iv0.x; iv[1] = iv0.y; iv[2] = iv0.z; iv[3] = iv0.w;
            iv[4] = iv1.x; iv[5] = iv1.y; iv[6] = iv1.z; iv[7] = iv1.w;
#pragma unroll
            for (int j = 0; j < 8; ++j) { bv[j] = -3.4e38f; bi[j] = 0; }
        }
        if (tv) {
            int r1 = t + k, r2 = t;
            float acc[8][8] = {};
#pragma unroll
            for (int h = 0; h < 2; ++h) {
                const float* Ag = refb + (size_t)(h * 32) * LPIX + r1 * 64;
                const float* Bg = lrb  + (size_t)(h * 32) * LPIX + r2 * 64;
                __syncthreads();                 // drain reads of previous half
#pragma unroll
                for (int it = 0; it < 8; ++it) {
                    int n = it * 64 + lane;      // f4 idx: c = n>>4, q = n&15
                    int c = n >> 4, q = n & 15;
                    *(float4*)&As[c * 64 + 4 * q] = *(const float4*)&Ag[(size_t)c * LPIX + 4 * q];
                    *(float4*)&Bs[c * 64 + 4 * q] = *(const float4*)&Bg[(size_t)c * LPIX + 4 * q];
                }
                __syncthreads();
                const float* Ap = As + rg * 8;
                const float* Bp = Bs + cg * 8;
#pragma unroll 4
                for (int kk = 0; kk < 32; ++kk) {
                    float4 a0 = *(const float4*)(Ap + kk * 64);
                    float4 a1 = *(const float4*)(Ap + kk * 64 + 4);
                    float4 b0 = *(const float4*)(Bp + kk * 64);
                    float4 b1 = *(const float4*)(Bp + kk * 64 + 4);
                    float av[8] = {a0.x, a0.y, a0.z, a0.w, a1.x, a1.y, a1.z, a1.w};
                    float bw[8] = {b0.x, b0.y, b0.z, b0.w, b1.x, b1.y, b1.z, b1.w};
#pragma unroll
                    for (int i = 0; i < 8; ++i)
#pragma unroll
                        for (int j = 0; j < 8; ++j) acc[i][j] = fmaf(av[i], bw[j], acc[i][j]);
                }
            }
            // x-band epilogue in registers (R3-validated):
            // E[r][c] = D[r-1][c-1] + D[r][c] + D[r+1][c+1]
            float up[7], lf[7], dn[8], rt[8], um, dpc;
#pragma unroll
            for (int q = 0; q < 7; ++q) up[q] = __shfl(acc[7][q], lane - 8, 64);
            um = __shfl(acc[7][7], lane - 9, 64);
#pragma unroll
            for (int q = 0; q < 7; ++q) lf[q] = __shfl(acc[q][7], lane - 1, 64);
#pragma unroll
            for (int q = 1; q < 8; ++q) dn[q] = __shfl(acc[0][q], lane + 8, 64);
            dpc = __shfl(acc[0][0], lane + 9, 64);
#pragma unroll
            for (int q = 1; q < 8; ++q) rt[q] = __shfl(acc[q][0], lane + 1, 64);
#pragma unroll
            for (int i = 0; i < 8; ++i) {
#pragma unroll
                for (int j = 0; j < 8; ++j) {
                    float dm, dpv;
                    if (i >= 1) dm = (j >= 1) ? acc[i - 1][j - 1] : (cgt ? lf[i - 1] : 0.f);
                    else        dm = rgt ? ((j >= 1) ? up[j - 1] : (cgt ? um : 0.f)) : 0.f;
                    if (i <= 6) dpv = (j <= 6) ? acc[i + 1][j + 1] : (clt ? rt[i + 1] : 0.f);
                    else        dpv = rlt ? ((j <= 6) ? dn[j + 1] : (clt ? dpc : 0.f)) : 0.f;
                    float e = dm + acc[i][j] + dpv;
                    float sv = P[i][j] + e;      // completed S(t-1)[rg*8+i][cg*8+j]
                    P[i][j] = Q[i][j] + e;
                    Q[i][j] = e;
                    if (fin) {
                        float v = sv * iv[i];
                        if (v > bv[j]) { bv[j] = v; bi[j] = i; }
                    }
                }
            }
        } else {
#pragma unroll
            for (int i = 0; i < 8; ++i)
#pragma unroll
                for (int j = 0; j < 8; ++j) {
                    float sv = P[i][j];
                    P[i][j] = Q[i][j];
                    Q[i][j] = 0.f;
                    if (fin) {
                        float v = sv * iv[i];
                        if (v > bv[j]) { bv[j] = v; bi[j] = i; }
                    }
                }
        }
        if (fin) {
            u64 key[8];
#pragma unroll
            for (int j = 0; j < 8; ++j) key[j] = packKey(bv[j], yprow + rg * 8 + bi[j]);
#pragma unroll
            for (int d = 8; d <= 32; d <<= 1)
#pragma unroll
                for (int j = 0; j < 8; ++j) {
                    u64 o = __shfl_xor(key[j], d, 64);
                    key[j] = key[j] > o ? key[j] : o;
                }
            if (rg == 0) {
                int cb = ((t - 1) << 6) + cg * 8;
#pragma unroll
                for (int j = 0; j < 8; ++j) atomicMax(&pkb[cb + j], key[j]);
            }
        }
    }
}

// ---- gather + fold: one wave per output pixel ----------------------------
__global__ __launch_bounds__(256) void gather_kernel(const u64* __restrict__ packed,
                                                     const float* __restrict__ refT,
                                                     float* __restrict__ Tt) {
    int b = blockIdx.y;
    int wave = threadIdx.x >> 6, lane = threadIdx.x & 63;
    int p = blockIdx.x * 4 + wave;       // 0..4095
    int py = p >> 6, px = p & 63;
    const u64* pk = packed + (size_t)b * LPIX;
    const float* rT = refT + (size_t)b * LPIX * 64;
    float acc = 0.f;
#pragma unroll
    for (int i = 0; i < 3; ++i)
#pragma unroll
        for (int j = 0; j < 3; ++j) {
            int qy = py + 1 - i, qx = px + 1 - j;
            if ((unsigned)qy >= 64u || (unsigned)qx >= 64u) continue;
            int aidx = (int)(~(unsigned int)pk[qy * 64 + qx]);
            int ry = (aidx >> 6) + i - 1, rx = (aidx & 63) + j - 1;
            if ((unsigned)ry >= 64u || (unsigned)rx >= 64u) continue;
            acc += rT[(size_t)(ry * 64 + rx) * 64 + lane];
        }
    Tt[((size_t)b * LPIX + p) * 64 + lane] = acc;
}

// ---- 1x1 conv: z[b][co][p] = w1[co][0:64]*lr + w1[co][64:128]*T + b1 -----
#define XST 36
__global__ __launch_bounds__(256) void conv1_kernel(const float* __restrict__ lr,
                                                    const float* __restrict__ Tt,
                                                    const float* __restrict__ w1,
                                                    const float* __restrict__ b1,
                                                    float* __restrict__ z) {
    __shared__ __align__(16) float xs[128 * XST];
    __shared__ __align__(16) float wsm[64 * 128];
    int pt = blockIdx.x, b = blockIdx.y, tid = threadIdx.x;
    for (int k = 0; k < 8; ++k) {
        int n = tid + 256 * k;           // 2048 float4s of w1
        *(float4*)&wsm[4 * n] = *(const float4*)&w1[4 * n];
    }
    const float* lrb = lr + (size_t)b * CCH * LPIX + pt * 32;
    for (int k = 0; k < 2; ++k) {
        int n = tid + 256 * k;           // 512 f4: c = n>>3, q = n&7
        int c = n >> 3, q = n & 7;
        *(float4*)&xs[c * XST + 4 * q] = *(const float4*)&lrb[(size_t)c * LPIX + 4 * q];
    }
    const float* Tb = Tt + ((size_t)b * LPIX + pt * 32) * 64;
    for (int k = 0; k < 2; ++k) {
        int n = tid + 256 * k;           // 512 f4: p = n>>4, cq = n&15
        int p = n >> 4, cq = n & 15;
        float4 v = *(const float4*)&Tb[p * 64 + 4 * cq];
        xs[(64 + 4 * cq + 0) * XST + p] = v.x;
        xs[(64 + 4 * cq + 1) * XST + p] = v.y;
        xs[(64 + 4 * cq + 2) * XST + p] = v.z;
        xs[(64 + 4 * cq + 3) * XST + p] = v.w;
    }
    __syncthreads();
    int p = tid & 31, g = tid >> 5;      // g: 8 groups of 8 output channels
    float acc[8];
#pragma unroll
    for (int t = 0; t < 8; ++t) acc[t] = b1[g * 8 + t];
    for (int c = 0; c < 128; ++c) {
        float xv = xs[c * XST + p];
#pragma unroll
        for (int t = 0; t < 8; ++t) acc[t] = fmaf(wsm[(g * 8 + t) * 128 + c], xv, acc[t]);
    }
    float* zb = z + (size_t)b * CCH * LPIX + pt * 32;
#pragma unroll
    for (int t = 0; t < 8; ++t) zb[(size_t)(g * 8 + t) * LPIX + p] = acc[t];
}

// ---- depthwise 3x3 + bias + relu -> out ----------------------------------
__global__ __launch_bounds__(256) void dw_kernel(const float* __restrict__ z,
                                                 const float* __restrict__ wd,
                                                 const float* __restrict__ bd,
                                                 float* __restrict__ out) {
    __shared__ __align__(16) float zs[4096];
    int c = blockIdx.x, b = blockIdx.y, tid = threadIdx.x;
    const float* zb = z + ((size_t)b * CCH + c) * LPIX;
    for (int k = 0; k < 4; ++k) {
        int n = tid + 256 * k;
        *(float4*)&zs[4 * n] = *(const float4*)&zb[4 * n];
    }
    __syncthreads();
    float w[9];
#pragma unroll
    for (int t = 0; t < 9; ++t) w[t] = wd[c * 9 + t];
    float bias = bd[c];
    float* ob = out + ((size_t)b * CCH + c) * LPIX;
    for (int s = 0; s < 16; ++s) {
        int p = tid + 256 * s;
        int y = p >> 6, x = p & 63;
        float acc = bias;
#pragma unroll
        for (int i = 0; i < 3; ++i) {
            int yy = y + i - 1;
            if ((unsigned)yy >= 64u) continue;
#pragma unroll
            for (int j = 0; j < 3; ++j) {
                int xx = x + j - 1;
                if ((unsigned)xx >= 64u) continue;
                acc = fmaf(zs[yy * 64 + xx], w[i * 3 + j], acc);
            }
        }
        ob[p] = fmaxf(acc, 0.f);
    }
}

extern "C" void kernel_launch(void* const* d_in, const int* in_sizes, int n_in,
                              void* d_out, int out_size, void* d_ws, size_t ws_size,
                              hipStream_t stream) {
    const float* lr  = (const float*)d_in[0];
    const float* ref = (const float*)d_in[1];
    const float* w1  = (const float*)d_in[2];
    const float* b1  = (const float*)d_in[3];
    const float* wd  = (const float*)d_in[4];
    const float* bd  = (const float*)d_in[5];
    float* out = (float*)d_out;

    float* ws = (float*)d_ws;
    float* refT = ws;                                   // 1,048,576 f
    float* ssq  = refT + (size_t)1048576;               //    16,384 f
    float* inv  = ssq + 16384;                          //    16,384 f
    u64* packed = (u64*)(inv + 16384);                  //    16,384 u64
    float* Tt = (float*)(packed + 16384);               // 1,048,576 f
    float* z  = Tt + (size_t)1048576;                   // 1,048,576 f
    // total ~12.8 MiB of d_ws (no E tensor anymore)

    hipMemsetAsync(packed, 0, (size_t)BATCH * LPIX * sizeof(u64), stream);
    prep_kernel<<<dim3(64, BATCH), 256, 0, stream>>>(ref, refT, ssq);
    invnorm_kernel<<<dim3(64), 256, 0, stream>>>(ssq, inv);
    diag_kernel<<<dim3(127, 8, BATCH), 64, 0, stream>>>(ref, lr, inv, packed);
    gather_kernel<<<dim3(1024, BATCH), 256, 0, stream>>>(packed, refT, Tt);
    conv1_kernel<<<dim3(128, BATCH), 256, 0, stream>>>(lr, Tt, w1, b1, z);
    dw_kernel<<<dim3(64, BATCH), 256, 0, stream>>>(z, wd, bd, out);
}